// Round 9
// baseline (175.204 us; speedup 1.0000x reference)
//
#include <hip/hip_runtime.h>
#include <stdint.h>

// Problem constants: t_q=64, t_k=128, b=32, n=1024
//   query (64,32,1024) f32 ; keys (128,32,1024) f32 ; Wq,Wk (1024,1024) f32
//   out0 = context (64,32,1024) f32 ; out1 = scores_softmax (64,32,128) f32

typedef __attribute__((ext_vector_type(8))) short bf16x8;
typedef __attribute__((ext_vector_type(4))) float f32x4;

#define C2_SCALE 2.8853900817779268f   // 2*log2(e)

__device__ __forceinline__ unsigned short f2bf(float x) {
    union { float f; uint32_t u; } v; v.f = x;
    uint32_t u = v.u;
    u += 0x7fffu + ((u >> 16) & 1u);   // round-to-nearest-even
    return (unsigned short)(u >> 16);
}

__device__ __forceinline__ float wave_sum(float x) {
#pragma unroll
    for (int off = 32; off; off >>= 1) x += __shfl_xor(x, off);
    return x;
}
__device__ __forceinline__ float wave_max(float x) {
#pragma unroll
    for (int off = 32; off; off >>= 1) x = fmaxf(x, __shfl_xor(x, off));
    return x;
}

// async 16B global -> LDS (wave-uniform base + lane*16 semantics)
__device__ __forceinline__ void gl2lds16(const void* g, void* l) {
    __builtin_amdgcn_global_load_lds(
        (const __attribute__((address_space(1))) void*)g,
        (__attribute__((address_space(3))) void*)l, 16, 0, 0);
}

// ------- f32 -> bf16 conversion of all 4 tensors + fused vnorm (blk 8192) ---
__global__ __launch_bounds__(256) void convert_kernel(
    const float* __restrict__ q, const float* __restrict__ k,
    const float* __restrict__ wq, const float* __restrict__ wk,
    unsigned short* __restrict__ qb, unsigned short* __restrict__ kb,
    unsigned short* __restrict__ wqb, unsigned short* __restrict__ wkb,
    const float* __restrict__ la, const float* __restrict__ ns,
    float* __restrict__ v) {
    __shared__ float red[4], red2[4];
    if (blockIdx.x == 8192) {
        // vnorm: v = la/||la|| * ns; v[1024] = sum(v)
        int tid = threadIdx.x, w = tid >> 6;
        float s = 0.f;
        for (int i = tid; i < 1024; i += 256) { float x = la[i]; s += x * x; }
        s = wave_sum(s);
        if ((tid & 63) == 0) red[w] = s;
        __syncthreads();
        float scale = rsqrtf(red[0] + red[1] + red[2] + red[3]) * ns[0];
        float vp = 0.f;
        for (int i = tid; i < 1024; i += 256) { float vv = la[i] * scale; v[i] = vv; vp += vv; }
        vp = wave_sum(vp);
        if ((tid & 63) == 0) red2[w] = vp;
        __syncthreads();
        if (tid == 0) v[1024] = red2[0] + red2[1] + red2[2] + red2[3];
        return;
    }
    int idx = blockIdx.x * 256 + threadIdx.x;   // float4 index; 2097152 total
    int e = idx * 4;
    const float* src; unsigned short* dst; int off;
    if (e < 2097152)      { src = q;  dst = qb;  off = e; }
    else if (e < 6291456) { src = k;  dst = kb;  off = e - 2097152; }
    else if (e < 7340032) { src = wq; dst = wqb; off = e - 6291456; }
    else                  { src = wk; dst = wkb; off = e - 7340032; }
    float4 xv = *(const float4*)(src + off);
    ushort4 o;
    o.x = f2bf(xv.x); o.y = f2bf(xv.y); o.z = f2bf(xv.z); o.w = f2bf(xv.w);
    *(ushort4*)(dst + off) = o;
}

// ---------------- combined projection GEMM: C = A * B^T (bf16 -> f32) -------
// rows 0..2047    -> pq  = qb * wqb^T                  (raw)
// rows 2048..6143 -> ek  = exp2(kb * wkb^T * C2_SCALE) (pre-exp'd for score)
// BK=64 (halves barrier count vs R8), 64-row x 128-col tile, 4 waves 2x2
// (wave tile 32x64, acc 2x4): per iter 16 MFMA : 12 ds_read : 6 stage insts.
// Rows are 128 B in LDS -> naive reads would 16-way bank-conflict; k-chunks
// are XOR-swizzled (col = kc ^ (row&7)) at stage AND read -> 2-way (free),
// while global_load_lds lane-contiguity (dest = base + lane*16) is preserved.
// Grid (8, 96) = 768 blocks = 3-4 blocks/CU.
__global__ __launch_bounds__(256) void proj_gemm(
    const unsigned short* __restrict__ qb, const unsigned short* __restrict__ kb,
    const unsigned short* __restrict__ wqb, const unsigned short* __restrict__ wkb,
    float* __restrict__ pq, float* __restrict__ ek) {
    __shared__ unsigned short As[64 * 64];    // 8 KB  [row][kcol swizzled]
    __shared__ unsigned short Bs[128 * 64];   // 16 KB [col][kcol swizzled]
    int col0 = blockIdx.x * 128;   // 8 col tiles
    int row0 = blockIdx.y * 64;    // 96 row tiles
    const unsigned short* A; const unsigned short* Bm; float* C; int arow; bool is_k;
    if (row0 < 2048) { A = qb; Bm = wqb; C = pq; arow = row0;        is_k = false; }
    else             { A = kb; Bm = wkb; C = ek; arow = row0 - 2048; is_k = true; }
    int tid = threadIdx.x;
    int w = tid >> 6, lane = tid & 63;
    int wm = w >> 1, wn = w & 1;          // 2x2 waves
    int ml = lane & 15, quad = lane >> 4;

    // staging: chunk c = tid + t*256 -> LDS byte c*16; row = c>>3, kc_lds = c&7
    // fetch global k-chunk kc_g = kc_lds ^ (row&7) so LDS[row][kc^(row&7)] = chunk kc
    int srow = tid >> 3;
    int kxor = (tid & 7) ^ (srow & 7);
    const unsigned short* ga = A + (arow + srow) * 1024 + kxor * 8;
    const unsigned short* gb = Bm + (col0 + srow) * 1024 + kxor * 8;
    unsigned short* la = &As[tid * 8];
    unsigned short* lb = &Bs[tid * 8];

    f32x4 acc[2][4];
#pragma unroll
    for (int i = 0; i < 2; i++)
#pragma unroll
        for (int j = 0; j < 4; j++) acc[i][j] = (f32x4)(0.f);

    int axor = ml & 7;   // (row&7) for all reads below (rows = base16k + ml)
    for (int k0 = 0; k0 < 1024; k0 += 64) {
        __syncthreads();                 // previous iteration's LDS reads done
        gl2lds16(ga + k0, la);                               // A rows 0..31
        gl2lds16(ga + 32 * 1024 + k0, la + 256 * 8);         // A rows 32..63
#pragma unroll
        for (int t = 0; t < 4; t++)
            gl2lds16(gb + t * 32 * 1024 + k0, lb + t * 256 * 8);
        __syncthreads();                 // staging drained
#pragma unroll
        for (int kb2 = 0; kb2 < 2; kb2++) {
            int kcol = ((kb2 * 4 + quad) ^ axor) * 8;
            bf16x8 a[2], b[4];
#pragma unroll
            for (int i = 0; i < 2; i++)
                a[i] = *(const bf16x8*)&As[(wm * 32 + i * 16 + ml) * 64 + kcol];
#pragma unroll
            for (int j = 0; j < 4; j++)
                b[j] = *(const bf16x8*)&Bs[(wn * 64 + j * 16 + ml) * 64 + kcol];
#pragma unroll
            for (int i = 0; i < 2; i++)
#pragma unroll
                for (int j = 0; j < 4; j++)
                    acc[i][j] = __builtin_amdgcn_mfma_f32_16x16x32_bf16(a[i], b[j], acc[i][j], 0, 0, 0);
        }
    }

    // C/D layout: col = lane&15, row = quad*4 + reg
#pragma unroll
    for (int i = 0; i < 2; i++)
#pragma unroll
        for (int j = 0; j < 4; j++) {
            int colg = col0 + wn * 64 + j * 16 + ml;
#pragma unroll
            for (int r = 0; r < 4; r++) {
                int row = arow + wm * 32 + i * 16 + quad * 4 + r;
                float val = acc[i][j][r];
                if (is_k) val = __builtin_amdgcn_exp2f(val * C2_SCALE);
                C[row * 1024 + colg] = val;
            }
        }
}

// ---------------- score partial sums (split-u) ------------------------------
// Grid (32 b, 16 qt, 2 uh) = 1024 blocks, 512 thr -> 4 blocks/CU, ~2x the
// wave concurrency of R8 at the SAME instantaneous per-CU stream bytes
// (32 waves x half-row == 16 waves x full row) — R3-thrash-safe by design.
// TRIPWIRE: FETCH > 100 MB here means L2 thrash -> revert to R8 shape.
// No barriers, no LDS: each wave owns k=kk*8+w, lane owns u = uh*512 +
// i*256 + lane*4 (i<2); partial a_j written raw to psc (disjoint slots).
__global__ __launch_bounds__(512, 8) void score_part(
    const float* __restrict__ pq, const float* __restrict__ ekbuf,
    const float* __restrict__ bias, const float* __restrict__ v,
    float* __restrict__ psc) {
    int b = blockIdx.x;
    int qt = blockIdx.y;
    int uh = blockIdx.z;
    int q0 = qt * 4;
    int tid = threadIdx.x;
    int w = tid >> 6, lane = tid & 63;   // w in 0..7
    int ub = uh * 512;

    float4 ej[4][2];
    float4 vv[2];
#pragma unroll
    for (int i = 0; i < 2; i++) {
        int u0 = ub + i * 256 + lane * 4;
        float4 bb = *(const float4*)(bias + u0);
        vv[i] = *(const float4*)(v + u0);
#pragma unroll
        for (int j = 0; j < 4; j++) {
            float4 p = *(const float4*)(pq + ((q0 + j) * 32 + b) * 1024 + u0);
            ej[j][i].x = __builtin_amdgcn_exp2f((p.x + bb.x) * C2_SCALE);
            ej[j][i].y = __builtin_amdgcn_exp2f((p.y + bb.y) * C2_SCALE);
            ej[j][i].z = __builtin_amdgcn_exp2f((p.z + bb.z) * C2_SCALE);
            ej[j][i].w = __builtin_amdgcn_exp2f((p.w + bb.w) * C2_SCALE);
        }
    }

    float* out = psc + ((b * 16 + qt) * 2 + uh) * 512;
    const float* base = ekbuf + (w * 32 + b) * 1024 + ub + lane * 4;
    for (int kk = 0; kk < 16; kk++) {
        int k = kk * 8 + w;
        const float* cur = base + kk * 262144;
        float a0 = 0.f, a1 = 0.f, a2 = 0.f, a3 = 0.f;
#pragma unroll
        for (int i = 0; i < 2; i++) {
            float4 e4 = *(const float4*)(cur + i * 256);   // ek values
            float4 v4 = vv[i];
#pragma unroll
            for (int j = 0; j < 4; j++) {
                float4 e = ej[j][i];
                float acc = (j == 0) ? a0 : (j == 1) ? a1 : (j == 2) ? a2 : a3;
                float A1 = fmaf(e.x, e4.x, 1.f);
                float B1 = fmaf(e.y, e4.y, 1.f);
                float num = fmaf(v4.x, B1, v4.y * A1);
                acc = fmaf(num, __builtin_amdgcn_rcpf(A1 * B1), acc);
                float A2 = fmaf(e.z, e4.z, 1.f);
                float B2 = fmaf(e.w, e4.w, 1.f);
                float num2 = fmaf(v4.z, B2, v4.w * A2);
                acc = fmaf(num2, __builtin_amdgcn_rcpf(A2 * B2), acc);
                if (j == 0) a0 = acc; else if (j == 1) a1 = acc;
                else if (j == 2) a2 = acc; else a3 = acc;
            }
        }
        a0 = wave_sum(a0); a1 = wave_sum(a1); a2 = wave_sum(a2); a3 = wave_sum(a3);
        if (lane == 0) {
            out[0 * 128 + k] = a0;
            out[1 * 128 + k] = a1;
            out[2 * 128 + k] = a2;
            out[3 * 128 + k] = a3;
        }
    }
}

// ---------------- finalize: combine halves, softmax, context ----------------
__global__ __launch_bounds__(512) void score_fin(
    const float* __restrict__ psc, const float* __restrict__ keys,
    const float* __restrict__ v,
    float* __restrict__ out_ctx, float* __restrict__ out_sc) {
    __shared__ float sc[4][128];
    const float L2E = 1.4426950408889634f;
    int b = blockIdx.x;
    int qt = blockIdx.y;
    int q0 = qt * 4;
    int tid = threadIdx.x;
    int w = tid >> 6, lane = tid & 63;
    float vsum = v[1024];

    {
        int j = tid >> 7, k = tid & 127;
        const float* p = psc + (b * 16 + qt) * 1024 + j * 128 + k;
        sc[j][k] = vsum - 2.f * (p[0] + p[512]);
    }
    __syncthreads();

    // softmax over k (128): waves 0..3 handle q-row j=w; lanes cover k, k+64
    if (w < 4) {
        int j = w;
        float s1 = sc[j][lane], s2 = sc[j][lane + 64];
        float m = wave_max(fmaxf(s1, s2));
        float e1 = __builtin_amdgcn_exp2f((s1 - m) * L2E);
        float e2 = __builtin_amdgcn_exp2f((s2 - m) * L2E);
        float ssum = wave_sum(e1 + e2);
        float inv = __builtin_amdgcn_rcpf(ssum);
        float p1 = e1 * inv, p2 = e2 * inv;
        sc[j][lane] = p1; sc[j][lane + 64] = p2;
        float* o = out_sc + ((q0 + j) * 32 + b) * 128;
        o[lane] = p1; o[lane + 64] = p2;
    }
    __syncthreads();

    // context[j][n] = sum_k p[j][k] * keys[k][b][n]; thread owns 2 n's, 4 rows
    {
        int n0 = tid * 2;
        const float* kbase = keys + b * 1024 + n0;
        float c0x = 0, c0y = 0, c1x = 0, c1y = 0;
        float c2x = 0, c2y = 0, c3x = 0, c3y = 0;
        for (int k = 0; k < 128; k++) {
            float2 kv = *(const float2*)(kbase + k * 32768);
            float p0 = sc[0][k], p1 = sc[1][k], p2 = sc[2][k], p3 = sc[3][k];
            c0x = fmaf(p0, kv.x, c0x); c0y = fmaf(p0, kv.y, c0y);
            c1x = fmaf(p1, kv.x, c1x); c1y = fmaf(p1, kv.y, c1y);
            c2x = fmaf(p2, kv.x, c2x); c2y = fmaf(p2, kv.y, c2y);
            c3x = fmaf(p3, kv.x, c3x); c3y = fmaf(p3, kv.y, c3y);
        }
        float2 o;
        o.x = c0x; o.y = c0y; *(float2*)(out_ctx + ((q0 + 0) * 32 + b) * 1024 + n0) = o;
        o.x = c1x; o.y = c1y; *(float2*)(out_ctx + ((q0 + 1) * 32 + b) * 1024 + n0) = o;
        o.x = c2x; o.y = c2y; *(float2*)(out_ctx + ((q0 + 2) * 32 + b) * 1024 + n0) = o;
        o.x = c3x; o.y = c3y; *(float2*)(out_ctx + ((q0 + 3) * 32 + b) * 1024 + n0) = o;
    }
}

extern "C" void kernel_launch(void* const* d_in, const int* in_sizes, int n_in,
                              void* d_out, int out_size, void* d_ws, size_t ws_size,
                              hipStream_t stream) {
    const float* query = (const float*)d_in[0];
    const float* keys  = (const float*)d_in[1];
    const float* Wq    = (const float*)d_in[2];
    const float* Wk    = (const float*)d_in[3];
    const float* la    = (const float*)d_in[4];
    const float* ns    = (const float*)d_in[5];
    const float* bias  = (const float*)d_in[6];

    float* out_ctx = (float*)d_out;             // 64*32*1024
    float* out_sc  = (float*)d_out + 2097152;   // 64*32*128

    char* ws = (char*)d_ws;                     // ~42 MB
    float* v  = (float*)(ws);                   // 1025 floats
    float* pq = (float*)(ws + 8192);            // 8 MB
    float* ek = (float*)(ws + 8192 + 8388608);  // 16 MB
    unsigned short* qb  = (unsigned short*)(ws + 8192 + 8388608 + 16777216);
    unsigned short* kb  = qb + 2097152;
    unsigned short* wqb = kb + 4194304;
    unsigned short* wkb = wqb + 1048576;
    // psc (2 MB) aliases qb (4 MB): qb is dead once proj_gemm completes,
    // and score_part runs after proj_gemm in stream order.
    float* psc = (float*)qb;

    convert_kernel<<<8193, 256, 0, stream>>>(query, keys, Wq, Wk, qb, kb, wqb, wkb,
                                             la, ns, v);
    proj_gemm<<<dim3(8, 96), 256, 0, stream>>>(qb, kb, wqb, wkb, pq, ek);
    score_part<<<dim3(32, 16, 2), 512, 0, stream>>>(pq, ek, bias, v, psc);
    score_fin<<<dim3(32, 16), 512, 0, stream>>>(psc, keys, v, out_ctx, out_sc);
}

// Round 10
// 169.480 us; speedup vs baseline: 1.0338x; 1.0338x over previous
//
#include <hip/hip_runtime.h>
#include <stdint.h>

// Problem constants: t_q=64, t_k=128, b=32, n=1024
//   query (64,32,1024) f32 ; keys (128,32,1024) f32 ; Wq,Wk (1024,1024) f32
//   out0 = context (64,32,1024) f32 ; out1 = scores_softmax (64,32,128) f32

typedef __attribute__((ext_vector_type(8))) short bf16x8;
typedef __attribute__((ext_vector_type(4))) float f32x4;

#define C2_SCALE 2.8853900817779268f   // 2*log2(e)

__device__ __forceinline__ unsigned short f2bf(float x) {
    union { float f; uint32_t u; } v; v.f = x;
    uint32_t u = v.u;
    u += 0x7fffu + ((u >> 16) & 1u);   // round-to-nearest-even
    return (unsigned short)(u >> 16);
}

__device__ __forceinline__ float wave_sum(float x) {
#pragma unroll
    for (int off = 32; off; off >>= 1) x += __shfl_xor(x, off);
    return x;
}
__device__ __forceinline__ float wave_sum32(float x) {   // within 32-lane halves
#pragma unroll
    for (int off = 16; off; off >>= 1) x += __shfl_xor(x, off);
    return x;
}
__device__ __forceinline__ float wave_max(float x) {
#pragma unroll
    for (int off = 32; off; off >>= 1) x = fmaxf(x, __shfl_xor(x, off));
    return x;
}

// async 16B global -> LDS (wave-uniform base + lane*16 semantics)
__device__ __forceinline__ void gl2lds16(const void* g, void* l) {
    __builtin_amdgcn_global_load_lds(
        (const __attribute__((address_space(1))) void*)g,
        (__attribute__((address_space(3))) void*)l, 16, 0, 0);
}

// ------- f32 -> bf16 conversion of all 4 tensors + fused vnorm (blk 8192) ---
__global__ __launch_bounds__(256) void convert_kernel(
    const float* __restrict__ q, const float* __restrict__ k,
    const float* __restrict__ wq, const float* __restrict__ wk,
    unsigned short* __restrict__ qb, unsigned short* __restrict__ kb,
    unsigned short* __restrict__ wqb, unsigned short* __restrict__ wkb,
    const float* __restrict__ la, const float* __restrict__ ns,
    float* __restrict__ v) {
    __shared__ float red[4], red2[4];
    if (blockIdx.x == 8192) {
        // vnorm: v = la/||la|| * ns; v[1024] = sum(v)
        int tid = threadIdx.x, w = tid >> 6;
        float s = 0.f;
        for (int i = tid; i < 1024; i += 256) { float x = la[i]; s += x * x; }
        s = wave_sum(s);
        if ((tid & 63) == 0) red[w] = s;
        __syncthreads();
        float scale = rsqrtf(red[0] + red[1] + red[2] + red[3]) * ns[0];
        float vp = 0.f;
        for (int i = tid; i < 1024; i += 256) { float vv = la[i] * scale; v[i] = vv; vp += vv; }
        vp = wave_sum(vp);
        if ((tid & 63) == 0) red2[w] = vp;
        __syncthreads();
        if (tid == 0) v[1024] = red2[0] + red2[1] + red2[2] + red2[3];
        return;
    }
    int idx = blockIdx.x * 256 + threadIdx.x;   // float4 index; 2097152 total
    int e = idx * 4;
    const float* src; unsigned short* dst; int off;
    if (e < 2097152)      { src = q;  dst = qb;  off = e; }
    else if (e < 6291456) { src = k;  dst = kb;  off = e - 2097152; }
    else if (e < 7340032) { src = wq; dst = wqb; off = e - 6291456; }
    else                  { src = wk; dst = wkb; off = e - 7340032; }
    float4 xv = *(const float4*)(src + off);
    ushort4 o;
    o.x = f2bf(xv.x); o.y = f2bf(xv.y); o.z = f2bf(xv.z); o.w = f2bf(xv.w);
    *(ushort4*)(dst + off) = o;
}

// ---------------- combined projection GEMM: C = A * B^T (bf16 -> f32) -------
// rows 0..2047    -> pq  = qb * wqb^T                  (raw)
// rows 2048..6143 -> ek  = exp2(kb * wkb^T * C2_SCALE) (pre-exp'd for score)
// BK=64, 64-row x 128-col tile, 4 waves 2x2 (wave tile 32x64, acc 2x4).
// XOR-swizzled LDS k-chunks (col = kc ^ (row&7)) -> 2-way conflicts (free).
// Grid (8, 96) = 768 blocks = 3 blocks/CU.
__global__ __launch_bounds__(256) void proj_gemm(
    const unsigned short* __restrict__ qb, const unsigned short* __restrict__ kb,
    const unsigned short* __restrict__ wqb, const unsigned short* __restrict__ wkb,
    float* __restrict__ pq, float* __restrict__ ek) {
    __shared__ unsigned short As[64 * 64];    // 8 KB  [row][kcol swizzled]
    __shared__ unsigned short Bs[128 * 64];   // 16 KB [col][kcol swizzled]
    int col0 = blockIdx.x * 128;   // 8 col tiles
    int row0 = blockIdx.y * 64;    // 96 row tiles
    const unsigned short* A; const unsigned short* Bm; float* C; int arow; bool is_k;
    if (row0 < 2048) { A = qb; Bm = wqb; C = pq; arow = row0;        is_k = false; }
    else             { A = kb; Bm = wkb; C = ek; arow = row0 - 2048; is_k = true; }
    int tid = threadIdx.x;
    int w = tid >> 6, lane = tid & 63;
    int wm = w >> 1, wn = w & 1;          // 2x2 waves
    int ml = lane & 15, quad = lane >> 4;

    int srow = tid >> 3;
    int kxor = (tid & 7) ^ (srow & 7);
    const unsigned short* ga = A + (arow + srow) * 1024 + kxor * 8;
    const unsigned short* gb = Bm + (col0 + srow) * 1024 + kxor * 8;
    unsigned short* la = &As[tid * 8];
    unsigned short* lb = &Bs[tid * 8];

    f32x4 acc[2][4];
#pragma unroll
    for (int i = 0; i < 2; i++)
#pragma unroll
        for (int j = 0; j < 4; j++) acc[i][j] = (f32x4)(0.f);

    int axor = ml & 7;
    for (int k0 = 0; k0 < 1024; k0 += 64) {
        __syncthreads();
        gl2lds16(ga + k0, la);
        gl2lds16(ga + 32 * 1024 + k0, la + 256 * 8);
#pragma unroll
        for (int t = 0; t < 4; t++)
            gl2lds16(gb + t * 32 * 1024 + k0, lb + t * 256 * 8);
        __syncthreads();
#pragma unroll
        for (int kb2 = 0; kb2 < 2; kb2++) {
            int kcol = ((kb2 * 4 + quad) ^ axor) * 8;
            bf16x8 a[2], b[4];
#pragma unroll
            for (int i = 0; i < 2; i++)
                a[i] = *(const bf16x8*)&As[(wm * 32 + i * 16 + ml) * 64 + kcol];
#pragma unroll
            for (int j = 0; j < 4; j++)
                b[j] = *(const bf16x8*)&Bs[(wn * 64 + j * 16 + ml) * 64 + kcol];
#pragma unroll
            for (int i = 0; i < 2; i++)
#pragma unroll
                for (int j = 0; j < 4; j++)
                    acc[i][j] = __builtin_amdgcn_mfma_f32_16x16x32_bf16(a[i], b[j], acc[i][j], 0, 0, 0);
        }
    }

    // C/D layout: col = lane&15, row = quad*4 + reg
#pragma unroll
    for (int i = 0; i < 2; i++)
#pragma unroll
        for (int j = 0; j < 4; j++) {
            int colg = col0 + wn * 64 + j * 16 + ml;
#pragma unroll
            for (int r = 0; r < 4; r++) {
                int row = arow + wm * 32 + i * 16 + quad * 4 + r;
                float val = acc[i][j][r];
                if (is_k) val = __builtin_amdgcn_exp2f(val * C2_SCALE);
                C[row * 1024 + colg] = val;
            }
        }
}

// ---------------- score partial sums (split-u, quarter) ---------------------
// Grid (32 b, 16 qt, 4 uh) = 2048 blocks, 512 thr, <=64 VGPR -> 4 blocks/CU
// capacity (32 waves/CU) with 2x block supply for load balance.
// Wave remap: 2 k-groups x 32 u-lanes (g = lane>>5, ul = lane&31):
//   - 8 u per lane (2 float4) -> ej stays 32 VGPR
//   - reduction = 5 shuffle steps over 32 lanes, one inst serves both k-groups
//   - kk = 8 iters, k = kk*16 + w*2 + g
// Pairing identity: v0/(1+A)+v1/(1+B) = [v0*B1+v1*A1]*rcp(A1*B1).
// TRIPWIRE: FETCH > 100 MB -> L2 thrash -> revert.
__global__ __launch_bounds__(512, 8) void score_part(
    const float* __restrict__ pq, const float* __restrict__ ekbuf,
    const float* __restrict__ bias, const float* __restrict__ v,
    float* __restrict__ psc) {
    int b = blockIdx.x;
    int qt = blockIdx.y;
    int uh = blockIdx.z;           // 0..3
    int q0 = qt * 4;
    int tid = threadIdx.x;
    int w = tid >> 6, lane = tid & 63;   // w in 0..7
    int g = lane >> 5, ul = lane & 31;
    int ub = uh * 256;

    float4 ej[4][2];
    float4 vv[2];
#pragma unroll
    for (int i = 0; i < 2; i++) {
        int u0 = ub + ul * 4 + i * 128;
        float4 bb = *(const float4*)(bias + u0);
        vv[i] = *(const float4*)(v + u0);
#pragma unroll
        for (int j = 0; j < 4; j++) {
            float4 p = *(const float4*)(pq + ((q0 + j) * 32 + b) * 1024 + u0);
            ej[j][i].x = __builtin_amdgcn_exp2f((p.x + bb.x) * C2_SCALE);
            ej[j][i].y = __builtin_amdgcn_exp2f((p.y + bb.y) * C2_SCALE);
            ej[j][i].z = __builtin_amdgcn_exp2f((p.z + bb.z) * C2_SCALE);
            ej[j][i].w = __builtin_amdgcn_exp2f((p.w + bb.w) * C2_SCALE);
        }
    }

    float* out = psc + ((b * 16 + qt) * 4 + uh) * 512;
    const float* base = ekbuf + b * 1024 + ub + ul * 4;   // + k*32768
    for (int kk = 0; kk < 8; kk++) {
        int k = kk * 16 + w * 2 + g;
        const float* cur = base + k * 32768;
        float a0 = 0.f, a1 = 0.f, a2 = 0.f, a3 = 0.f;
#pragma unroll
        for (int i = 0; i < 2; i++) {
            float4 e4 = *(const float4*)(cur + i * 128);   // ek values
            float4 v4 = vv[i];
#pragma unroll
            for (int j = 0; j < 4; j++) {
                float4 e = ej[j][i];
                float acc = (j == 0) ? a0 : (j == 1) ? a1 : (j == 2) ? a2 : a3;
                float A1 = fmaf(e.x, e4.x, 1.f);
                float B1 = fmaf(e.y, e4.y, 1.f);
                float num = fmaf(v4.x, B1, v4.y * A1);
                acc = fmaf(num, __builtin_amdgcn_rcpf(A1 * B1), acc);
                float A2 = fmaf(e.z, e4.z, 1.f);
                float B2 = fmaf(e.w, e4.w, 1.f);
                float num2 = fmaf(v4.z, B2, v4.w * A2);
                acc = fmaf(num2, __builtin_amdgcn_rcpf(A2 * B2), acc);
                if (j == 0) a0 = acc; else if (j == 1) a1 = acc;
                else if (j == 2) a2 = acc; else a3 = acc;
            }
        }
        a0 = wave_sum32(a0); a1 = wave_sum32(a1);
        a2 = wave_sum32(a2); a3 = wave_sum32(a3);
        if (ul == 0) {
            out[0 * 128 + k] = a0;
            out[1 * 128 + k] = a1;
            out[2 * 128 + k] = a2;
            out[3 * 128 + k] = a3;
        }
    }
}

// ---------------- finalize: combine quarters, softmax, context --------------
// Grid (32 b, 16 qt, 2 nh) = 1024 blocks -> 4 blocks/CU. Softmax computed in
// both nh blocks (cheap, deterministic); only nh==0 writes out_sc. Each block
// does the context GEMV for its n-half: thread owns 1 n, 4 q-rows.
__global__ __launch_bounds__(512) void score_fin(
    const float* __restrict__ psc, const float* __restrict__ keys,
    const float* __restrict__ v,
    float* __restrict__ out_ctx, float* __restrict__ out_sc) {
    __shared__ float sc[4][128];
    const float L2E = 1.4426950408889634f;
    int b = blockIdx.x;
    int qt = blockIdx.y;
    int nh = blockIdx.z;
    int q0 = qt * 4;
    int tid = threadIdx.x;
    int w = tid >> 6, lane = tid & 63;
    float vsum = v[1024];

    {
        int j = tid >> 7, k = tid & 127;
        const float* p = psc + (b * 16 + qt) * 2048 + j * 128 + k;
        sc[j][k] = vsum - 2.f * (p[0] + p[512] + p[1024] + p[1536]);
    }
    __syncthreads();

    // softmax over k (128): waves 0..3 handle q-row j=w; lanes cover k, k+64
    if (w < 4) {
        int j = w;
        float s1 = sc[j][lane], s2 = sc[j][lane + 64];
        float m = wave_max(fmaxf(s1, s2));
        float e1 = __builtin_amdgcn_exp2f((s1 - m) * L2E);
        float e2 = __builtin_amdgcn_exp2f((s2 - m) * L2E);
        float ssum = wave_sum(e1 + e2);
        float inv = __builtin_amdgcn_rcpf(ssum);
        float p1 = e1 * inv, p2 = e2 * inv;
        sc[j][lane] = p1; sc[j][lane + 64] = p2;
        if (nh == 0) {
            float* o = out_sc + ((q0 + j) * 32 + b) * 128;
            o[lane] = p1; o[lane + 64] = p2;
        }
    }
    __syncthreads();

    // context[j][n] = sum_k p[j][k] * keys[k][b][n]; thread owns 1 n, 4 rows
    {
        int n0 = nh * 512 + tid;
        const float* kbase = keys + b * 1024 + n0;
        float c0 = 0, c1 = 0, c2 = 0, c3 = 0;
        for (int k = 0; k < 128; k++) {
            float kv = kbase[k * 32768];
            c0 = fmaf(sc[0][k], kv, c0);
            c1 = fmaf(sc[1][k], kv, c1);
            c2 = fmaf(sc[2][k], kv, c2);
            c3 = fmaf(sc[3][k], kv, c3);
        }
        out_ctx[((q0 + 0) * 32 + b) * 1024 + n0] = c0;
        out_ctx[((q0 + 1) * 32 + b) * 1024 + n0] = c1;
        out_ctx[((q0 + 2) * 32 + b) * 1024 + n0] = c2;
        out_ctx[((q0 + 3) * 32 + b) * 1024 + n0] = c3;
    }
}

extern "C" void kernel_launch(void* const* d_in, const int* in_sizes, int n_in,
                              void* d_out, int out_size, void* d_ws, size_t ws_size,
                              hipStream_t stream) {
    const float* query = (const float*)d_in[0];
    const float* keys  = (const float*)d_in[1];
    const float* Wq    = (const float*)d_in[2];
    const float* Wk    = (const float*)d_in[3];
    const float* la    = (const float*)d_in[4];
    const float* ns    = (const float*)d_in[5];
    const float* bias  = (const float*)d_in[6];

    float* out_ctx = (float*)d_out;             // 64*32*1024
    float* out_sc  = (float*)d_out + 2097152;   // 64*32*128

    char* ws = (char*)d_ws;                     // ~42 MB
    float* v  = (float*)(ws);                   // 1025 floats
    float* pq = (float*)(ws + 8192);            // 8 MB
    float* ek = (float*)(ws + 8192 + 8388608);  // 16 MB
    unsigned short* qb  = (unsigned short*)(ws + 8192 + 8388608 + 16777216);
    unsigned short* kb  = qb + 2097152;
    unsigned short* wqb = kb + 4194304;
    unsigned short* wkb = wqb + 1048576;
    // psc (4 MB) aliases qb (4 MB): qb is dead once proj_gemm completes,
    // and score_part runs after proj_gemm in stream order.
    float* psc = (float*)qb;

    convert_kernel<<<8193, 256, 0, stream>>>(query, keys, Wq, Wk, qb, kb, wqb, wkb,
                                             la, ns, v);
    proj_gemm<<<dim3(8, 96), 256, 0, stream>>>(qb, kb, wqb, wkb, pq, ek);
    score_part<<<dim3(32, 16, 4), 512, 0, stream>>>(pq, ek, bias, v, psc);
    score_fin<<<dim3(32, 16, 2), 512, 0, stream>>>(psc, keys, v, out_ctx, out_sc);
}